// Round 4
// baseline (257.556 us; speedup 1.0000x reference)
//
#include <hip/hip_runtime.h>
#include <hip/hip_bf16.h>

// Problem constants: N=32, C=3, H=W=512, A=512, SCALE=1, ITERS=5, thr0=4.0f.
#define AN 512
#define NB 32
#define HW 512

__device__ __forceinline__ float waveMax(float v) {
    #pragma unroll
    for (int off = 32; off > 0; off >>= 1) v = fmaxf(v, __shfl_xor(v, off, 64));
    return v;
}
__device__ __forceinline__ float waveSum(float v) {
    #pragma unroll
    for (int off = 32; off > 0; off >>= 1) v += __shfl_xor(v, off, 64);
    return v;
}

// ---------------------------------------------------------------------------
// Kernel 1: water-fill + inverse-CDF coords. One block = ONE WAVE per sample.
// 8 elements/lane; reductions = in-lane + shfl butterfly (zero barriers);
// cumsum = serial-in-lane + shfl_up wave scan of chunk totals.
// ---------------------------------------------------------------------------
__global__ __launch_bounds__(64) void waterfill_coords_kernel(
    const float* __restrict__ attx, const float* __restrict__ atty,
    float* __restrict__ gx, float* __restrict__ gy)
{
    __shared__ float axs[AN], ays[AN], csx[AN], csy[AN];
    const int n = blockIdx.x;
    const int l = threadIdx.x;   // 0..63

    float ax[8], ay[8];
    {
        const float4* px = (const float4*)(attx + n * AN);
        const float4* py = (const float4*)(atty + n * AN);
        float4 a = px[2 * l], b = px[2 * l + 1];
        float4 c = py[2 * l], d = py[2 * l + 1];
        ax[0] = a.x * 512.0f; ax[1] = a.y * 512.0f; ax[2] = a.z * 512.0f; ax[3] = a.w * 512.0f;
        ax[4] = b.x * 512.0f; ax[5] = b.y * 512.0f; ax[6] = b.z * 512.0f; ax[7] = b.w * 512.0f;
        ay[0] = c.x * 512.0f; ay[1] = c.y * 512.0f; ay[2] = c.z * 512.0f; ay[3] = c.w * 512.0f;
        ay[4] = d.x * 512.0f; ay[5] = d.y * 512.0f; ay[6] = d.z * 512.0f; ay[7] = d.w * 512.0f;
    }

    for (int j = 0; j < 5; ++j) {
        float mx = ax[0], my = ay[0];
        #pragma unroll
        for (int i = 1; i < 8; ++i) { mx = fmaxf(mx, ax[i]); my = fmaxf(my, ay[i]); }
        mx = waveMax(mx); my = waveMax(my);
        float thr = fminf(mx, my);
        if (j == 0) thr = fminf(thr, 4.0f);

        float sx = 0.0f, sy = 0.0f;
        #pragma unroll
        for (int i = 0; i < 8; ++i) {
            ax[i] = fminf(ax[i], thr); sx += ax[i];
            ay[i] = fminf(ay[i], thr); sy += ay[i];
        }
        sx = waveSum(sx); sy = waveSum(sy);
        const float cx = (512.0f - sx) * (1.0f / 512.0f);
        const float cy = (512.0f - sy) * (1.0f / 512.0f);
        #pragma unroll
        for (int i = 0; i < 8; ++i) { ax[i] += cx; ay[i] += cy; }
    }

    if (l == 0) { ax[0] = 1.0f; ay[0] = 1.0f; }   // ax.at[:,0].set(1.0)

    // in-lane inclusive scan
    float cxl[8], cyl[8];
    cxl[0] = ax[0]; cyl[0] = ay[0];
    #pragma unroll
    for (int i = 1; i < 8; ++i) { cxl[i] = cxl[i - 1] + ax[i]; cyl[i] = cyl[i - 1] + ay[i]; }
    // wave inclusive scan of chunk totals -> exclusive prefix
    float tx = cxl[7], ty = cyl[7];
    float ix = tx, iy = ty;
    #pragma unroll
    for (int s = 1; s < 64; s <<= 1) {
        float vx = __shfl_up(ix, s, 64);
        float vy = __shfl_up(iy, s, 64);
        if (l >= s) { ix += vx; iy += vy; }
    }
    const float ox = ix - tx, oy = iy - ty;

    #pragma unroll
    for (int i = 0; i < 8; ++i) {
        axs[8 * l + i] = ax[i]; csx[8 * l + i] = ox + cxl[i];
        ays[8 * l + i] = ay[i]; csy[8 * l + i] = oy + cyl[i];
    }
    __syncthreads();

    const float stepx = csx[AN - 1] * (1.0f / 512.0f);
    const float stepy = csy[AN - 1] * (1.0f / 512.0f);
    float outy[8], outx[8];
    #pragma unroll
    for (int i = 0; i < 8; ++i) {
        const int t = 8 * l + i;
        {   // height coords from (axs, csx)
            float tv = (float)(t + 1) * stepx;
            int lo = 0, hi = AN;
            while (lo < hi) { int mid = (lo + hi) >> 1; if (csx[mid] < tv) lo = mid + 1; else hi = mid; }
            int j = lo > (AN - 1) ? (AN - 1) : lo;
            float prev = (j > 0) ? csx[j - 1] : 0.0f;
            float frac = (tv - prev) / fmaxf(axs[j], 1e-12f);
            outy[i] = ((float)j + frac) * (2.0f / 512.0f) - 1.0f;
        }
        {   // width coords from (ays, csy)
            float tv = (float)(t + 1) * stepy;
            int lo = 0, hi = AN;
            while (lo < hi) { int mid = (lo + hi) >> 1; if (csy[mid] < tv) lo = mid + 1; else hi = mid; }
            int j = lo > (AN - 1) ? (AN - 1) : lo;
            float prev = (j > 0) ? csy[j - 1] : 0.0f;
            float frac = (tv - prev) / fmaxf(ays[j], 1e-12f);
            outx[i] = ((float)j + frac) * (2.0f / 512.0f) - 1.0f;
        }
    }
    ((float4*)(gy + n * AN))[2 * l]     = make_float4(outy[0], outy[1], outy[2], outy[3]);
    ((float4*)(gy + n * AN))[2 * l + 1] = make_float4(outy[4], outy[5], outy[6], outy[7]);
    ((float4*)(gx + n * AN))[2 * l]     = make_float4(outx[0], outx[1], outx[2], outx[3]);
    ((float4*)(gx + n * AN))[2 * l + 1] = make_float4(outx[4], outx[5], outx[6], outx[7]);
}

// ---------------------------------------------------------------------------
// Kernel 2: separable bilinear grid-sample via LDS row staging.
// 2 output rows per 256-thread block (128 thr/row, 4 px/thread INTERLEAVED:
// px = t2 + 128k so adjacent lanes gather at LDS stride ~1 -> conflict-free).
// 12 row slots (2 rows x {y0,y1} x 3 ch) staged with 6 float4 loads/thread.
// XCD swizzle: consecutive row-pairs land on the same XCD for L2 reuse of
// the overlapping source row.
// ---------------------------------------------------------------------------
__global__ __launch_bounds__(256) void grid_sample_kernel(
    const float* __restrict__ data, const float* __restrict__ gx,
    const float* __restrict__ gy, float* __restrict__ outS,
    float* __restrict__ outG)
{
    __shared__ float rows[12 * HW];   // slot r = c*4 + ypair, 24 KB
    const int t  = threadIdx.x;
    const int n  = blockIdx.y;
    const int bx = blockIdx.x;                       // 0..255
    const int pair = ((bx & 7) << 5) | (bx >> 3);    // 8 XCDs x 32 contiguous pairs
    const int hoA = pair * 2;
    const int rowsel = t >> 7;                       // 0/1
    const int t2 = t & 127;
    const int ho = hoA + rowsel;

    // y math for both rows
    const float2 gy2 = *(const float2*)(gy + n * AN + hoA);
    const float yA = (gy2.x + 1.0f) * 256.0f - 0.5f;
    const float yB = (gy2.y + 1.0f) * 256.0f - 0.5f;
    const float y0Af = floorf(yA), y0Bf = floorf(yB);
    int yy[4];
    yy[0] = (int)fminf(fmaxf(y0Af, 0.0f), 511.0f);
    yy[1] = (int)fminf(fmaxf(y0Af + 1.0f, 0.0f), 511.0f);
    yy[2] = (int)fminf(fmaxf(y0Bf, 0.0f), 511.0f);
    yy[3] = (int)fminf(fmaxf(y0Bf + 1.0f, 0.0f), 511.0f);

    // stage 12 source rows, 6 float4 loads per thread (all independent)
    const float* basen = data + (size_t)n * 3 * HW * HW;
    #pragma unroll
    for (int i = 0; i < 6; ++i) {
        const int idx = i * 256 + t;
        const int r   = idx >> 7;        // 0..11
        const int col = idx & 127;
        const int c = r >> 2, yp = r & 3;
        float4 v = ((const float4*)(basen + ((size_t)c * HW + yy[yp]) * HW))[col];
        ((float4*)(rows + r * HW))[col] = v;
    }
    __syncthreads();

    // my row's y weights (uniform per half-block)
    const float gyv = rowsel ? gy2.y : gy2.x;
    const float yv  = rowsel ? yB : yA;
    const float y0f = rowsel ? y0Bf : y0Af;
    const float wy1 = yv - y0f, wy0 = 1.0f - wy1;
    const float vy0 = ((y0f >= 0.0f) && (y0f < 512.0f)) ? 1.0f : 0.0f;
    const float vy1 = ((y0f >= -1.0f) && (y0f < 511.0f)) ? 1.0f : 0.0f;
    const int sbase = rowsel * 2;

    #pragma unroll
    for (int k = 0; k < 4; ++k) {
        const int wo = t2 + k * 128;
        const float gxv = gx[n * AN + wo];
        const float x = (gxv + 1.0f) * 256.0f - 0.5f;
        const float x0f = floorf(x);
        const float wx1 = x - x0f, wx0 = 1.0f - wx1;
        const float vx0 = ((x0f >= 0.0f) && (x0f < 512.0f)) ? 1.0f : 0.0f;
        const float vx1 = ((x0f >= -1.0f) && (x0f < 511.0f)) ? 1.0f : 0.0f;
        const int x0 = (int)fminf(fmaxf(x0f, 0.0f), 511.0f);
        const int x1 = (int)fminf(fmaxf(x0f + 1.0f, 0.0f), 511.0f);
        const float w00 = wx0 * wy0 * vx0 * vy0;
        const float w10 = wx1 * wy0 * vx1 * vy0;
        const float w01 = wx0 * wy1 * vx0 * vy1;
        const float w11 = wx1 * wy1 * vx1 * vy1;
        #pragma unroll
        for (int c = 0; c < 3; ++c) {
            const float* rp0 = rows + (c * 4 + sbase) * HW;
            const float* rp1 = rp0 + HW;
            outS[(((size_t)n * 3 + c) * HW + ho) * HW + wo] =
                rp0[x0] * w00 + rp0[x1] * w10 + rp1[x0] * w01 + rp1[x1] * w11;
        }
        *(float2*)(outG + (((size_t)n * HW + ho) * HW + wo) * 2) = make_float2(gxv, gyv);
    }
}

extern "C" void kernel_launch(void* const* d_in, const int* in_sizes, int n_in,
                              void* d_out, int out_size, void* d_ws, size_t ws_size,
                              hipStream_t stream) {
    const float* data = (const float*)d_in[0];   // (32,3,512,512)
    const float* attx = (const float*)d_in[1];   // (32,512)
    const float* atty = (const float*)d_in[2];   // (32,512)

    float* gx = (float*)d_ws;            // (32,512) width coords
    float* gy = gx + NB * AN;            // (32,512) height coords

    float* outS = (float*)d_out;                          // sampled (32,3,512,512)
    float* outG = outS + (size_t)NB * 3 * HW * HW;        // grid (32,512,512,2)

    waterfill_coords_kernel<<<NB, 64, 0, stream>>>(attx, atty, gx, gy);

    dim3 grid(HW / 2, NB);
    grid_sample_kernel<<<grid, 256, 0, stream>>>(data, gx, gy, outS, outG);
}